// Round 2
// baseline (1817.779 us; speedup 1.0000x reference)
//
#include <hip/hip_runtime.h>

#define N_NODES 100000
#define N_EDGES 3200000
#define D 64
#define EPS 1e-5f

// ---------------------------------------------------------------------------
// Fold GCNConv weight + FC weight into one 64x64:  Wc = W @ fw,  bc = b@fw+fb
// grid = 2 blocks (layer 1 / layer 2), 256 threads
// ---------------------------------------------------------------------------
__global__ __launch_bounds__(256) void combine_weights(
    const float* __restrict__ W1, const float* __restrict__ b1,
    const float* __restrict__ fw1, const float* __restrict__ fb1,
    const float* __restrict__ W2, const float* __restrict__ b2,
    const float* __restrict__ fw2, const float* __restrict__ fb2,
    float* __restrict__ Wc1, float* __restrict__ bc1,
    float* __restrict__ Wc2, float* __restrict__ bc2) {
  const float* W  = blockIdx.x ? W2  : W1;
  const float* fw = blockIdx.x ? fw2 : fw1;
  const float* b  = blockIdx.x ? b2  : b1;
  const float* fb = blockIdx.x ? fb2 : fb1;
  float* Wc = blockIdx.x ? Wc2 : Wc1;
  float* bc = blockIdx.x ? bc2 : bc1;

  __shared__ float sW[64 * 64];
  __shared__ float sf[64 * 64];
  for (int i = threadIdx.x; i < 4096; i += 256) { sW[i] = W[i]; sf[i] = fw[i]; }
  __syncthreads();
  for (int o = threadIdx.x; o < 4096; o += 256) {
    int i = o >> 6, j = o & 63;
    float acc = 0.f;
    #pragma unroll
    for (int k = 0; k < 64; ++k) acc += sW[i * 64 + k] * sf[k * 64 + j];
    Wc[o] = acc;
  }
  if (threadIdx.x < 64) {
    int j = threadIdx.x;
    float acc = fb[j];
    #pragma unroll
    for (int k = 0; k < 64; ++k) acc += b[k] * sf[k * 64 + j];
    bc[j] = acc;
  }
}

// deg[i] = 1 (self loop); zero the 4x64 BN-stat accumulators
__global__ void init_deg(float* __restrict__ deg, float* __restrict__ stats) {
  int i = blockIdx.x * blockDim.x + threadIdx.x;
  if (i < N_NODES) deg[i] = 1.0f;
  if (i < 256) stats[i] = 0.0f;
}

__global__ void deg_acc(const int* __restrict__ dst, float* __restrict__ deg) {
  int e = blockIdx.x * blockDim.x + threadIdx.x;
  if (e < N_EDGES) atomicAdd(&deg[dst[e]], 1.0f);
}

__global__ void make_dinv(float* __restrict__ deg) {
  int i = blockIdx.x * blockDim.x + threadIdx.x;
  if (i < N_NODES) deg[i] = rsqrtf(deg[i]);
}

// agg[i][:] = dinv[i]^2 * x[i][:]   (self-loop contribution, also zero-inits)
__global__ void agg_init_x(const float* __restrict__ x, const float* __restrict__ dinv,
                           float* __restrict__ agg) {
  int idx = blockIdx.x * blockDim.x + threadIdx.x;
  if (idx < N_NODES * D) {
    int i = idx >> 6;
    float di = dinv[i];
    agg[idx] = di * di * x[idx];
  }
}

// one wave per edge, lane = feature: agg[dst][lane] += dinv[s]*dinv[t]*x[src][lane]
__global__ void agg_edges_x(const int* __restrict__ src, const int* __restrict__ dst,
                            const float* __restrict__ dinv, const float* __restrict__ x,
                            float* __restrict__ agg) {
  long long idx = (long long)blockIdx.x * blockDim.x + threadIdx.x;
  int e = (int)(idx >> 6);
  int lane = (int)(idx & 63);
  if (e < N_EDGES) {
    int s = src[e], t = dst[e];
    float co = dinv[s] * dinv[t];
    atomicAdd(&agg[t * 64 + lane], co * x[s * 64 + lane]);
  }
}

// same but source values go through the fused BN-affine + ReLU of layer 1
__global__ void agg_init_y(const float* __restrict__ Y, const float* __restrict__ dinv,
                           const float* __restrict__ a, const float* __restrict__ c,
                           float* __restrict__ agg) {
  int idx = blockIdx.x * blockDim.x + threadIdx.x;
  if (idx < N_NODES * D) {
    int i = idx >> 6, j = idx & 63;
    float v = fmaxf(Y[idx] * a[j] + c[j], 0.f);
    float di = dinv[i];
    agg[idx] = di * di * v;
  }
}

__global__ void agg_edges_y(const int* __restrict__ src, const int* __restrict__ dst,
                            const float* __restrict__ dinv, const float* __restrict__ Y,
                            const float* __restrict__ a, const float* __restrict__ c,
                            float* __restrict__ agg) {
  long long idx = (long long)blockIdx.x * blockDim.x + threadIdx.x;
  int e = (int)(idx >> 6);
  int lane = (int)(idx & 63);
  if (e < N_EDGES) {
    int s = src[e], t = dst[e];
    float co = dinv[s] * dinv[t];
    float v = fmaxf(Y[s * 64 + lane] * a[lane] + c[lane], 0.f);
    atomicAdd(&agg[t * 64 + lane], co * v);
  }
}

// ---------------------------------------------------------------------------
// Y[64-row tile] = A @ Wc + bc, fused per-column sum / sum-of-squares partials
// block = 256 threads: col = tid&63, row-group = tid>>6 (16 rows each)
// ---------------------------------------------------------------------------
__global__ __launch_bounds__(256) void gemm_stats(
    const float* __restrict__ A, const float* __restrict__ Wc,
    const float* __restrict__ bc, float* __restrict__ Y,
    float* __restrict__ colsum, float* __restrict__ colsq) {
  __shared__ float sA[64 * 64];
  __shared__ float sW[64 * 64];
  __shared__ float sB[64];
  __shared__ float red[8][64];

  const int tid = threadIdx.x;
  const int c = tid & 63;
  const int rg = tid >> 6;
  const int rowBase = blockIdx.x * 64;

  for (int i = tid; i < 4096; i += 256) {
    int r = rowBase + (i >> 6);
    sA[i] = (r < N_NODES) ? A[r * 64 + (i & 63)] : 0.0f;
    sW[i] = Wc[i];
  }
  if (tid < 64) sB[tid] = bc[tid];
  __syncthreads();

  float acc[16];
  #pragma unroll
  for (int rr = 0; rr < 16; ++rr) acc[rr] = 0.f;
  const int rA = rg * 16;
  for (int k = 0; k < 64; ++k) {
    float w = sW[k * 64 + c];
    #pragma unroll
    for (int rr = 0; rr < 16; ++rr)
      acc[rr] += sA[(rA + rr) * 64 + k] * w;   // broadcast read (wave-uniform)
  }

  float psum = 0.f, psq = 0.f;
  #pragma unroll
  for (int rr = 0; rr < 16; ++rr) {
    int r = rowBase + rA + rr;
    if (r < N_NODES) {
      float y = acc[rr] + sB[c];
      Y[r * 64 + c] = y;
      psum += y;
      psq += y * y;
    }
  }
  red[rg][c] = psum;
  red[rg + 4][c] = psq;
  __syncthreads();
  if (tid < 64) {
    float s = red[0][c] + red[1][c] + red[2][c] + red[3][c];
    float q = red[4][c] + red[5][c] + red[6][c] + red[7][c];
    atomicAdd(&colsum[c], s);
    atomicAdd(&colsq[c], q);
  }
}

// fold BN into per-column scale/shift: a = g*rsqrt(var+eps), c = bt - mu*a
__global__ void finalize_stats(const float* __restrict__ colsum, const float* __restrict__ colsq,
                               const float* __restrict__ g, const float* __restrict__ bt,
                               float* __restrict__ a, float* __restrict__ c) {
  int j = threadIdx.x;
  if (j < 64) {
    float mu = colsum[j] * (1.0f / N_NODES);
    float var = colsq[j] * (1.0f / N_NODES) - mu * mu;
    float s = rsqrtf(var + EPS) * g[j];
    a[j] = s;
    c[j] = bt[j] - mu * s;
  }
}

// out = relu(Y*a + c), in place on d_out
__global__ void final_norm(float* __restrict__ Y, const float* __restrict__ a,
                           const float* __restrict__ c) {
  int idx = blockIdx.x * blockDim.x + threadIdx.x;
  if (idx < N_NODES * D) {
    int j = idx & 63;
    Y[idx] = fmaxf(Y[idx] * a[j] + c[j], 0.f);
  }
}

extern "C" void kernel_launch(void* const* d_in, const int* in_sizes, int n_in,
                              void* d_out, int out_size, void* d_ws, size_t ws_size,
                              hipStream_t stream) {
  const float* x   = (const float*)d_in[0];
  const int*   src = (const int*)d_in[1];          // edge_index row 0
  const int*   dst = src + N_EDGES;                // edge_index row 1
  const float* W1  = (const float*)d_in[2];
  const float* b1  = (const float*)d_in[3];
  const float* fw1 = (const float*)d_in[4];
  const float* fb1 = (const float*)d_in[5];
  const float* g1  = (const float*)d_in[6];
  const float* bt1 = (const float*)d_in[7];
  const float* W2  = (const float*)d_in[8];
  const float* b2  = (const float*)d_in[9];
  const float* fw2 = (const float*)d_in[10];
  const float* fb2 = (const float*)d_in[11];
  const float* g2  = (const float*)d_in[12];
  const float* bt2 = (const float*)d_in[13];

  float* Y = (float*)d_out;                        // N x 64, reused y1 -> y2 -> out

  // workspace layout (floats) -- NOTE: no trailing backslashes in comments!
  float* ws   = (float*)d_ws;
  float* agg  = ws;                                // N*64 = 6,400,000
  float* dinv = agg + (long long)N_NODES * D;      // N   (holds deg, then rsqrt)
  float* Wc1  = dinv + N_NODES;                    // 4096
  float* bc1  = Wc1 + 4096;                        // 64
  float* Wc2  = bc1 + 64;                          // 4096
  float* bc2  = Wc2 + 4096;                        // 64
  float* sum1 = bc2 + 64;                          // 64  (sum1..sq2 contiguous 256)
  float* sq1  = sum1 + 64;                         // 64
  float* sum2 = sq1 + 64;                          // 64
  float* sq2  = sum2 + 64;                         // 64
  float* a1   = sq2 + 64;
  float* c1   = a1 + 64;
  float* a2   = c1 + 64;
  float* c2   = a2 + 64;

  const int nd = N_NODES * D;                      // 6,400,000
  dim3 blk(256);

  combine_weights<<<2, blk, 0, stream>>>(W1, b1, fw1, fb1, W2, b2, fw2, fb2,
                                         Wc1, bc1, Wc2, bc2);
  init_deg<<<(N_NODES + 255) / 256, blk, 0, stream>>>(dinv, sum1);
  deg_acc<<<(N_EDGES + 255) / 256, blk, 0, stream>>>(dst, dinv);
  make_dinv<<<(N_NODES + 255) / 256, blk, 0, stream>>>(dinv);

  // layer 1
  agg_init_x<<<(nd + 255) / 256, blk, 0, stream>>>(x, dinv, agg);
  agg_edges_x<<<(N_EDGES * 64 + 255) / 256, blk, 0, stream>>>(src, dst, dinv, x, agg);
  gemm_stats<<<(N_NODES + 63) / 64, blk, 0, stream>>>(agg, Wc1, bc1, Y, sum1, sq1);
  finalize_stats<<<1, 64, 0, stream>>>(sum1, sq1, g1, bt1, a1, c1);

  // layer 2 (BN-affine+ReLU of layer 1 fused into the gather)
  agg_init_y<<<(nd + 255) / 256, blk, 0, stream>>>(Y, dinv, a1, c1, agg);
  agg_edges_y<<<(N_EDGES * 64 + 255) / 256, blk, 0, stream>>>(src, dst, dinv, Y, a1, c1, agg);
  gemm_stats<<<(N_NODES + 63) / 64, blk, 0, stream>>>(agg, Wc2, bc2, Y, sum2, sq2);
  finalize_stats<<<1, 64, 0, stream>>>(sum2, sq2, g2, bt2, a2, c2);

  final_norm<<<(nd + 255) / 256, blk, 0, stream>>>(Y, a2, c2);
}

// Round 3
// 845.045 us; speedup vs baseline: 2.1511x; 2.1511x over previous
//
#include <hip/hip_runtime.h>

#define N_NODES 100000
#define N_EDGES 3200000
#define D 64
#define EPS 1e-5f
#define SCAN_CHUNK 1024
#define NB_SCAN ((N_NODES + SCAN_CHUNK - 1) / SCAN_CHUNK)   // 98

// ---------------------------------------------------------------------------
// Fold GCNConv weight + FC weight into one 64x64:  Wc = W @ fw,  bc = b@fw+fb
// ---------------------------------------------------------------------------
__global__ __launch_bounds__(256) void combine_weights(
    const float* __restrict__ W1, const float* __restrict__ b1,
    const float* __restrict__ fw1, const float* __restrict__ fb1,
    const float* __restrict__ W2, const float* __restrict__ b2,
    const float* __restrict__ fw2, const float* __restrict__ fb2,
    float* __restrict__ Wc1, float* __restrict__ bc1,
    float* __restrict__ Wc2, float* __restrict__ bc2) {
  const float* W  = blockIdx.x ? W2  : W1;
  const float* fw = blockIdx.x ? fw2 : fw1;
  const float* b  = blockIdx.x ? b2  : b1;
  const float* fb = blockIdx.x ? fb2 : fb1;
  float* Wc = blockIdx.x ? Wc2 : Wc1;
  float* bc = blockIdx.x ? bc2 : bc1;

  __shared__ float sW[64 * 64];
  __shared__ float sf[64 * 64];
  for (int i = threadIdx.x; i < 4096; i += 256) { sW[i] = W[i]; sf[i] = fw[i]; }
  __syncthreads();
  for (int o = threadIdx.x; o < 4096; o += 256) {
    int i = o >> 6, j = o & 63;
    float acc = 0.f;
    #pragma unroll
    for (int k = 0; k < 64; ++k) acc += sW[i * 64 + k] * sf[k * 64 + j];
    Wc[o] = acc;
  }
  if (threadIdx.x < 64) {
    int j = threadIdx.x;
    float acc = fb[j];
    #pragma unroll
    for (int k = 0; k < 64; ++k) acc += b[k] * sf[k * 64 + j];
    bc[j] = acc;
  }
}

// zero edge-count histogram + BN stat accumulators
__global__ void zero_init(int* __restrict__ cnt, float* __restrict__ stats) {
  int i = blockIdx.x * blockDim.x + threadIdx.x;
  if (i < N_NODES) cnt[i] = 0;
  if (i < 256) stats[i] = 0.0f;
}

__global__ void hist_dst(const int* __restrict__ dst, int* __restrict__ cnt) {
  int e = blockIdx.x * blockDim.x + threadIdx.x;
  if (e < N_EDGES) atomicAdd(&cnt[dst[e]], 1);
}

// dinv[i] = rsqrt(deg) with deg = cnt + 1 (self loop)
__global__ void make_dinv(const int* __restrict__ cnt, float* __restrict__ dinv) {
  int i = blockIdx.x * blockDim.x + threadIdx.x;
  if (i < N_NODES) dinv[i] = rsqrtf((float)cnt[i] + 1.0f);
}

// ---- 3-kernel exclusive prefix sum of cnt -> off -----------------------------
__global__ __launch_bounds__(256) void scan_blocks(const int* __restrict__ cnt,
                                                   int* __restrict__ off,
                                                   int* __restrict__ bsum) {
  __shared__ int ts[256];
  const int tid = threadIdx.x;
  const int base = blockIdx.x * SCAN_CHUNK + tid * 4;
  int v[4];
  #pragma unroll
  for (int j = 0; j < 4; ++j) v[j] = (base + j < N_NODES) ? cnt[base + j] : 0;
  int run = 0;
  #pragma unroll
  for (int j = 0; j < 4; ++j) { int t = v[j]; v[j] = run; run += t; }
  ts[tid] = run;
  __syncthreads();
  for (int o = 1; o < 256; o <<= 1) {
    int add = (tid >= o) ? ts[tid - o] : 0;
    __syncthreads();
    ts[tid] += add;
    __syncthreads();
  }
  int excl = ts[tid] - run;          // exclusive prefix of this thread's chunk
  #pragma unroll
  for (int j = 0; j < 4; ++j)
    if (base + j < N_NODES) off[base + j] = excl + v[j];
  if (tid == 0) bsum[blockIdx.x] = ts[255];
}

__global__ void scan_totals(int* __restrict__ bsum) {
  __shared__ int ts[128];
  const int tid = threadIdx.x;
  int v = (tid < NB_SCAN) ? bsum[tid] : 0;
  ts[tid] = v;
  __syncthreads();
  for (int o = 1; o < 128; o <<= 1) {
    int add = (tid >= o) ? ts[tid - o] : 0;
    __syncthreads();
    ts[tid] += add;
    __syncthreads();
  }
  if (tid < NB_SCAN) bsum[tid] = ts[tid] - v;   // exclusive
}

__global__ void add_offsets(int* __restrict__ off, const int* __restrict__ bsum,
                            int* __restrict__ cur) {
  int i = blockIdx.x * blockDim.x + threadIdx.x;
  if (i < N_NODES) {
    int o = off[i] + bsum[i / SCAN_CHUNK];
    off[i] = o;
    cur[i] = o;
  } else if (i == N_NODES) {
    off[N_NODES] = N_EDGES;
  }
}

// scatter edges into CSR order, precomputing w = dinv[s]*dinv[t]
__global__ void scatter_edges(const int* __restrict__ src, const int* __restrict__ dst,
                              const float* __restrict__ dinv, int* __restrict__ cur,
                              int* __restrict__ eSrc, float* __restrict__ eW) {
  int e = blockIdx.x * blockDim.x + threadIdx.x;
  if (e < N_EDGES) {
    int s = src[e], t = dst[e];
    int pos = atomicAdd(&cur[t], 1);
    eSrc[pos] = s;
    eW[pos] = dinv[s] * dinv[t];
  }
}

// ---------------------------------------------------------------------------
// CSR aggregation: one wave per node, lane = feature. No atomics.
// ---------------------------------------------------------------------------
__global__ __launch_bounds__(256) void agg_csr_x(
    const int* __restrict__ off, const int* __restrict__ eSrc,
    const float* __restrict__ eW, const float* __restrict__ X,
    const float* __restrict__ dinv, float* __restrict__ agg) {
  const int wid = (blockIdx.x * 256 + threadIdx.x) >> 6;
  const int lane = threadIdx.x & 63;
  if (wid >= N_NODES) return;
  const int s0 = off[wid], s1 = off[wid + 1];
  const float dt = dinv[wid];
  float acc = dt * dt * X[wid * 64 + lane];
  int e = s0;
  for (; e + 4 <= s1; e += 4) {
    int u0 = eSrc[e], u1 = eSrc[e + 1], u2 = eSrc[e + 2], u3 = eSrc[e + 3];
    float w0 = eW[e], w1 = eW[e + 1], w2 = eW[e + 2], w3 = eW[e + 3];
    float v0 = X[u0 * 64 + lane];
    float v1 = X[u1 * 64 + lane];
    float v2 = X[u2 * 64 + lane];
    float v3 = X[u3 * 64 + lane];
    acc = fmaf(w0, v0, acc);
    acc = fmaf(w1, v1, acc);
    acc = fmaf(w2, v2, acc);
    acc = fmaf(w3, v3, acc);
  }
  for (; e < s1; ++e) acc = fmaf(eW[e], X[eSrc[e] * 64 + lane], acc);
  agg[wid * 64 + lane] = acc;
}

// layer-2 variant: gathered values pass through fused BN-affine + ReLU
__global__ __launch_bounds__(256) void agg_csr_y(
    const int* __restrict__ off, const int* __restrict__ eSrc,
    const float* __restrict__ eW, const float* __restrict__ Y,
    const float* __restrict__ dinv, const float* __restrict__ a,
    const float* __restrict__ c, float* __restrict__ agg) {
  const int wid = (blockIdx.x * 256 + threadIdx.x) >> 6;
  const int lane = threadIdx.x & 63;
  if (wid >= N_NODES) return;
  const float aj = a[lane], cj = c[lane];
  const int s0 = off[wid], s1 = off[wid + 1];
  const float dt = dinv[wid];
  float acc = dt * dt * fmaxf(fmaf(Y[wid * 64 + lane], aj, cj), 0.f);
  int e = s0;
  for (; e + 4 <= s1; e += 4) {
    int u0 = eSrc[e], u1 = eSrc[e + 1], u2 = eSrc[e + 2], u3 = eSrc[e + 3];
    float w0 = eW[e], w1 = eW[e + 1], w2 = eW[e + 2], w3 = eW[e + 3];
    float v0 = fmaxf(fmaf(Y[u0 * 64 + lane], aj, cj), 0.f);
    float v1 = fmaxf(fmaf(Y[u1 * 64 + lane], aj, cj), 0.f);
    float v2 = fmaxf(fmaf(Y[u2 * 64 + lane], aj, cj), 0.f);
    float v3 = fmaxf(fmaf(Y[u3 * 64 + lane], aj, cj), 0.f);
    acc = fmaf(w0, v0, acc);
    acc = fmaf(w1, v1, acc);
    acc = fmaf(w2, v2, acc);
    acc = fmaf(w3, v3, acc);
  }
  for (; e < s1; ++e)
    acc = fmaf(eW[e], fmaxf(fmaf(Y[eSrc[e] * 64 + lane], aj, cj), 0.f), acc);
  agg[wid * 64 + lane] = acc;
}

// ---------------------------------------------------------------------------
// Y[64-row tile] = A @ Wc + bc, fused per-column sum / sum-of-squares partials
// ---------------------------------------------------------------------------
__global__ __launch_bounds__(256) void gemm_stats(
    const float* __restrict__ A, const float* __restrict__ Wc,
    const float* __restrict__ bc, float* __restrict__ Y,
    float* __restrict__ colsum, float* __restrict__ colsq) {
  __shared__ float sA[64 * 64];
  __shared__ float sW[64 * 64];
  __shared__ float sB[64];
  __shared__ float red[8][64];

  const int tid = threadIdx.x;
  const int c = tid & 63;
  const int rg = tid >> 6;
  const int rowBase = blockIdx.x * 64;

  for (int i = tid; i < 4096; i += 256) {
    int r = rowBase + (i >> 6);
    sA[i] = (r < N_NODES) ? A[r * 64 + (i & 63)] : 0.0f;
    sW[i] = Wc[i];
  }
  if (tid < 64) sB[tid] = bc[tid];
  __syncthreads();

  float acc[16];
  #pragma unroll
  for (int rr = 0; rr < 16; ++rr) acc[rr] = 0.f;
  const int rA = rg * 16;
  for (int k = 0; k < 64; ++k) {
    float w = sW[k * 64 + c];
    #pragma unroll
    for (int rr = 0; rr < 16; ++rr)
      acc[rr] += sA[(rA + rr) * 64 + k] * w;
  }

  float psum = 0.f, psq = 0.f;
  #pragma unroll
  for (int rr = 0; rr < 16; ++rr) {
    int r = rowBase + rA + rr;
    if (r < N_NODES) {
      float y = acc[rr] + sB[c];
      Y[r * 64 + c] = y;
      psum += y;
      psq += y * y;
    }
  }
  red[rg][c] = psum;
  red[rg + 4][c] = psq;
  __syncthreads();
  if (tid < 64) {
    float s = red[0][c] + red[1][c] + red[2][c] + red[3][c];
    float q = red[4][c] + red[5][c] + red[6][c] + red[7][c];
    atomicAdd(&colsum[c], s);
    atomicAdd(&colsq[c], q);
  }
}

__global__ void finalize_stats(const float* __restrict__ colsum, const float* __restrict__ colsq,
                               const float* __restrict__ g, const float* __restrict__ bt,
                               float* __restrict__ a, float* __restrict__ c) {
  int j = threadIdx.x;
  if (j < 64) {
    float mu = colsum[j] * (1.0f / N_NODES);
    float var = colsq[j] * (1.0f / N_NODES) - mu * mu;
    float s = rsqrtf(var + EPS) * g[j];
    a[j] = s;
    c[j] = bt[j] - mu * s;
  }
}

__global__ void final_norm(float* __restrict__ Y, const float* __restrict__ a,
                           const float* __restrict__ c) {
  int idx = blockIdx.x * blockDim.x + threadIdx.x;
  if (idx < N_NODES * D) {
    int j = idx & 63;
    Y[idx] = fmaxf(fmaf(Y[idx], a[j], c[j]), 0.f);
  }
}

extern "C" void kernel_launch(void* const* d_in, const int* in_sizes, int n_in,
                              void* d_out, int out_size, void* d_ws, size_t ws_size,
                              hipStream_t stream) {
  const float* x   = (const float*)d_in[0];
  const int*   src = (const int*)d_in[1];          // edge_index row 0
  const int*   dst = src + N_EDGES;                // edge_index row 1
  const float* W1  = (const float*)d_in[2];
  const float* b1  = (const float*)d_in[3];
  const float* fw1 = (const float*)d_in[4];
  const float* fb1 = (const float*)d_in[5];
  const float* g1  = (const float*)d_in[6];
  const float* bt1 = (const float*)d_in[7];
  const float* W2  = (const float*)d_in[8];
  const float* b2  = (const float*)d_in[9];
  const float* fw2 = (const float*)d_in[10];
  const float* fb2 = (const float*)d_in[11];
  const float* g2  = (const float*)d_in[12];
  const float* bt2 = (const float*)d_in[13];

  float* Y = (float*)d_out;                        // N x 64, reused y1 -> y2 -> out

  // workspace layout (~53 MB)
  float* ws   = (float*)d_ws;
  float* agg  = ws;                                // N*64 floats
  float* dinv = agg + (size_t)N_NODES * D;         // N floats
  float* eW   = dinv + N_NODES;                    // E floats
  int*   eSrc = (int*)(eW + N_EDGES);              // E ints
  int*   cnt  = eSrc + N_EDGES;                    // N ints
  int*   off  = cnt + N_NODES;                     // N+1 ints
  int*   cur  = off + N_NODES + 1;                 // N ints
  int*   bsum = cur + N_NODES;                     // 128 ints
  float* Wc1  = (float*)(bsum + 128);              // 4096
  float* bc1  = Wc1 + 4096;                        // 64
  float* Wc2  = bc1 + 64;                          // 4096
  float* bc2  = Wc2 + 4096;                        // 64
  float* sum1 = bc2 + 64;                          // 64  (sum1..sq2 contiguous 256)
  float* sq1  = sum1 + 64;
  float* sum2 = sq1 + 64;
  float* sq2  = sum2 + 64;
  float* a1   = sq2 + 64;
  float* c1   = a1 + 64;
  float* a2   = c1 + 64;
  float* c2   = a2 + 64;

  const int nd = N_NODES * D;
  dim3 blk(256);

  combine_weights<<<2, blk, 0, stream>>>(W1, b1, fw1, fb1, W2, b2, fw2, fb2,
                                         Wc1, bc1, Wc2, bc2);

  // ---- CSR build (shared by both layers) ----
  zero_init<<<(N_NODES + 255) / 256, blk, 0, stream>>>(cnt, sum1);
  hist_dst<<<(N_EDGES + 255) / 256, blk, 0, stream>>>(dst, cnt);
  make_dinv<<<(N_NODES + 255) / 256, blk, 0, stream>>>(cnt, dinv);
  scan_blocks<<<NB_SCAN, blk, 0, stream>>>(cnt, off, bsum);
  scan_totals<<<1, 128, 0, stream>>>(bsum);
  add_offsets<<<(N_NODES + 1 + 255) / 256, blk, 0, stream>>>(off, bsum, cur);
  scatter_edges<<<(N_EDGES + 255) / 256, blk, 0, stream>>>(src, dst, dinv, cur, eSrc, eW);

  // ---- layer 1 ----
  agg_csr_x<<<(nd + 255) / 256, blk, 0, stream>>>(off, eSrc, eW, x, dinv, agg);
  gemm_stats<<<(N_NODES + 63) / 64, blk, 0, stream>>>(agg, Wc1, bc1, Y, sum1, sq1);
  finalize_stats<<<1, 64, 0, stream>>>(sum1, sq1, g1, bt1, a1, c1);

  // ---- layer 2 (BN-affine+ReLU of layer 1 fused into the gather) ----
  agg_csr_y<<<(nd + 255) / 256, blk, 0, stream>>>(off, eSrc, eW, Y, dinv, a1, c1, agg);
  gemm_stats<<<(N_NODES + 63) / 64, blk, 0, stream>>>(agg, Wc2, bc2, Y, sum2, sq2);
  finalize_stats<<<1, 64, 0, stream>>>(sum2, sq2, g2, bt2, a2, c2);

  final_norm<<<(nd + 255) / 256, blk, 0, stream>>>(Y, a2, c2);
}